// Round 1
// baseline (167.464 us; speedup 1.0000x reference)
//
#include <hip/hip_runtime.h>
#include <math.h>

#define NUM_E 6
#define DIM 1024
#define HID 256
#define NTOK 32768
#define NPB 4096   // tokens per batch (N)
#define TTYPE_UNKNOWN 5
#define ONE_MINUS_ALPHA 0.775f
#define FLOOR_TERM 0.0375f     // alpha * (1/E) = 0.225/6
#define GRP 16                 // unknown tokens per block in MLP kernel

// Closed-form top1 + hard-cap + combine for a probs vector of 6.
// dispatch = one_hot(argmax)*v, then TokenLevelHardCap, then normalize.
__device__ __forceinline__ void finalize_and_write(const float probs[NUM_E], float cap,
                                                   float* __restrict__ disp_out,
                                                   float* __restrict__ comb_out) {
    // argmax, lowest index wins ties (lax.top_k semantics)
    float v = probs[0];
    int bi = 0;
#pragma unroll
    for (int e = 1; e < NUM_E; ++e) {
        if (probs[e] > v) { v = probs[e]; bi = e; }
    }
    float excess = fmaxf(v - cap, 0.0f);
    float capped = v - excess;                 // min(v, cap)
    float hr_idx = fmaxf(cap - capped, 0.0f);  // headroom at the argmax slot
    // headroom at the 5 zero slots is relu(cap - 0) = cap (cap >= 0.5 always)
    float hsum = fmaxf(hr_idx + 5.0f * cap, 1e-8f);
    float disp[NUM_E];
    float other = excess * cap / hsum;
#pragma unroll
    for (int e = 0; e < NUM_E; ++e) disp[e] = other;
    disp[bi] = capped + excess * hr_idx / hsum;
    float s = 0.0f;
#pragma unroll
    for (int e = 0; e < NUM_E; ++e) s += disp[e];
    float inv = 1.0f / (s + 1e-8f);
#pragma unroll
    for (int e = 0; e < NUM_E; ++e) {
        disp_out[e] = disp[e];
        comb_out[e] = disp[e] * inv;
    }
}

// Kernel A: per-token classification. Known tokens -> write final output directly.
// Unknown tokens -> append index to compacted list in workspace.
__launch_bounds__(256)
__global__ void classify_kernel(const int* __restrict__ ttypes,
                                const int* __restrict__ tarr,
                                const float* __restrict__ base,
                                float* __restrict__ out,
                                int* __restrict__ cnt,
                                int* __restrict__ list) {
    int i = blockIdx.x * blockDim.x + threadIdx.x;
    if (i >= NTOK) return;
    int ty = ttypes[i];
    if (ty == TTYPE_UNKNOWN) {
        int pos = atomicAdd(cnt, 1);
        list[pos] = i;
        return;
    }
    int b = i / NPB;
    float tnorm = (float)tarr[b] / 1000.0f;
    float cap = 0.5f + 1.1f * tnorm;
    float probs[NUM_E];
#pragma unroll
    for (int e = 0; e < NUM_E; ++e)
        probs[e] = ONE_MINUS_ALPHA * base[ty * NUM_E + e] + FLOOR_TERM;
    finalize_and_write(probs, cap,
                       out + (size_t)i * NUM_E,
                       out + (size_t)NTOK * NUM_E + (size_t)i * NUM_E);
}

// Kernel B: MLP gate for unknown tokens only (compacted list).
// One block = GRP tokens x all 256 hidden columns. Thread tid owns h[:, tid].
__launch_bounds__(256)
__global__ void mlp_kernel(const float* __restrict__ tokens,
                           const int* __restrict__ tarr,
                           const float* __restrict__ W1,
                           const float* __restrict__ b1,
                           const float* __restrict__ W2,
                           const float* __restrict__ b2,
                           float* __restrict__ out,
                           const int* __restrict__ cnt,
                           const int* __restrict__ list) {
    __shared__ float xs[GRP][256];    // 16 KB: K-chunk of gathered token rows
    __shared__ float hs[GRP][HID];    // 16 KB: hidden activations
    __shared__ float w2s[HID * NUM_E];// 6 KB
    __shared__ float ls[GRP][NUM_E];
    __shared__ int   toks[GRP];

    int count = *cnt;
    int start = blockIdx.x * GRP;
    if (start >= count) return;
    int nv = min(GRP, count - start);
    int tid = threadIdx.x;

    if (tid < nv) toks[tid] = list[start + tid];
    for (int k = tid; k < HID * NUM_E; k += 256) w2s[k] = W2[k];
    __syncthreads();

    float acc[GRP];
#pragma unroll
    for (int r = 0; r < GRP; ++r) acc[r] = 0.0f;

    // Layer 1: h[r][tid] = sum_d x[r][d] * W1[d][tid], K chunked by 256
    for (int c = 0; c < DIM / 256; ++c) {
        // stage x chunk: thread tid loads column (c*256+tid) of each token row
#pragma unroll
        for (int r = 0; r < GRP; ++r) {
            float v = 0.0f;
            if (r < nv) v = tokens[(size_t)toks[r] * DIM + c * 256 + tid];
            xs[r][tid] = v;
        }
        __syncthreads();
        for (int d = 0; d < 256; d += 4) {
            float w0 = W1[(c * 256 + d + 0) * HID + tid];
            float w1_ = W1[(c * 256 + d + 1) * HID + tid];
            float w2_ = W1[(c * 256 + d + 2) * HID + tid];
            float w3_ = W1[(c * 256 + d + 3) * HID + tid];
#pragma unroll
            for (int r = 0; r < GRP; ++r) {
                acc[r] = fmaf(xs[r][d + 0], w0, acc[r]);
                acc[r] = fmaf(xs[r][d + 1], w1_, acc[r]);
                acc[r] = fmaf(xs[r][d + 2], w2_, acc[r]);
                acc[r] = fmaf(xs[r][d + 3], w3_, acc[r]);
            }
        }
        __syncthreads();
    }

    // exact GELU: x * 0.5 * (1 + erf(x/sqrt(2)))
    float bj = b1[tid];
#pragma unroll
    for (int r = 0; r < GRP; ++r) {
        float pre = acc[r] + bj;
        hs[r][tid] = 0.5f * pre * (1.0f + erff(pre * 0.70710678118654752f));
    }
    __syncthreads();

    // Layer 2: 96 active threads, one (token, expert) dot each
    if (tid < GRP * NUM_E) {
        int r = tid / NUM_E, e = tid % NUM_E;
        float s = 0.0f;
        for (int j = 0; j < HID; ++j) s = fmaf(hs[r][j], w2s[j * NUM_E + e], s);
        ls[r][e] = (s + b2[e]) / 0.1f;   // temperature
    }
    __syncthreads();

    // Finalize per token
    if (tid < nv) {
        int tokidx = toks[tid];
        int b = tokidx / NPB;
        float tnorm = (float)tarr[b] / 1000.0f;
        float cap = 0.5f + 1.1f * tnorm;
        float probs[NUM_E];
#pragma unroll
        for (int e = 0; e < NUM_E; ++e)
            probs[e] = ONE_MINUS_ALPHA * ls[tid][e] + FLOOR_TERM;
        finalize_and_write(probs, cap,
                           out + (size_t)tokidx * NUM_E,
                           out + (size_t)NTOK * NUM_E + (size_t)tokidx * NUM_E);
    }
}

extern "C" void kernel_launch(void* const* d_in, const int* in_sizes, int n_in,
                              void* d_out, int out_size, void* d_ws, size_t ws_size,
                              hipStream_t stream) {
    const float* tokens = (const float*)d_in[0];
    const int*   ttypes = (const int*)d_in[1];
    const int*   tarr   = (const int*)d_in[2];
    const float* W1     = (const float*)d_in[3];
    const float* b1     = (const float*)d_in[4];
    const float* W2     = (const float*)d_in[5];
    const float* b2     = (const float*)d_in[6];
    const float* base   = (const float*)d_in[7];
    float* out = (float*)d_out;

    int* cnt  = (int*)d_ws;
    int* list = (int*)d_ws + 64;   // 256 B offset; list worst case 128 KB

    hipMemsetAsync(cnt, 0, sizeof(int), stream);
    classify_kernel<<<NTOK / 256, 256, 0, stream>>>(ttypes, tarr, base, out, cnt, list);
    mlp_kernel<<<(NTOK + GRP - 1) / GRP, 256, 0, stream>>>(tokens, tarr, W1, b1, W2, b2,
                                                           out, cnt, list);
}